// Round 3
// baseline (243.257 us; speedup 1.0000x reference)
//
#include <hip/hip_runtime.h>
#include <hip/hip_cooperative_groups.h>

namespace cg = cooperative_groups;

// AnchorPositionalEncoding, fused single cooperative kernel:
//   phase 1: deg = rowsum(adj)  (1.074 GB stream, NT float4 loads)
//   grid.sync()
//   phase 2: nrm from per-block ssq partials; out = softmax(deg*deg[:64]/nrm) @ emb

constexpr int N_NODES = 16384;
constexpr int N_ANCH  = 64;
constexpr int HID     = 128;
constexpr int BLOCKS  = 512;                       // 2 blocks/CU -> coop-safe
constexpr int RPB     = N_NODES / BLOCKS;          // 32 rows/block
constexpr int RPW     = RPB / 4;                   // 8 rows/wave (phase 1)

typedef float f4 __attribute__((ext_vector_type(4)));

__global__ __launch_bounds__(256, 4) void fused_kernel(const float* __restrict__ adj,
                                                       const float* __restrict__ emb,
                                                       float* __restrict__ out,
                                                       float* __restrict__ deg,
                                                       float* __restrict__ ssq_part) {
    __shared__ float s_emb[N_ANCH * HID];   // 32 KiB
    __shared__ float s_w[4][N_ANCH];
    __shared__ float s_sp[4];
    __shared__ float s_red[4];

    const int t = threadIdx.x, lane = t & 63, wid = t >> 6;

    // stage emb early — independent of phase 1
    for (int i = t; i < N_ANCH * HID / 4; i += 256)
        reinterpret_cast<f4*>(s_emb)[i] = reinterpret_cast<const f4*>(emb)[i];

    // ---------------- phase 1: stream row sums ----------------
    const int row0 = blockIdx.x * RPB + wid * RPW;
    float ssq = 0.0f;
    for (int r = 0; r < RPW; ++r) {
        const int row = row0 + r;
        const f4* __restrict__ p =
            reinterpret_cast<const f4*>(adj) + (size_t)row * (N_NODES / 4) + lane;
        float s = 0.0f;
        for (int c = 0; c < 4; ++c) {              // 16 x 16B loads in flight
            f4 v[16];                               // static-indexed -> registers
#pragma unroll
            for (int i = 0; i < 16; ++i)
                v[i] = __builtin_nontemporal_load(p + c * 1024 + i * 64);
#pragma unroll
            for (int i = 0; i < 16; ++i)
                s += (v[i].x + v[i].y) + (v[i].z + v[i].w);
        }
#pragma unroll
        for (int off = 32; off > 0; off >>= 1) s += __shfl_down(s, off, 64);
        if (lane == 0) { deg[row] = s; ssq = fmaf(s, s, ssq); }
    }
    if (lane == 0) s_sp[wid] = ssq;
    __syncthreads();
    if (t == 0) ssq_part[blockIdx.x] = (s_sp[0] + s_sp[1]) + (s_sp[2] + s_sp[3]);

    cg::this_grid().sync();

    // ---------------- phase 2: norm + softmax @ emb ----------------
    // norm from 512 partials (fixed tree, redundant per block -> deterministic)
    float ss = ssq_part[t] + ssq_part[t + 256];
#pragma unroll
    for (int off = 32; off > 0; off >>= 1) ss += __shfl_down(ss, off, 64);
    if (lane == 0) s_red[wid] = ss;
    __syncthreads();
    const float inv_nrm =
        1.0f / (sqrtf((s_red[0] + s_red[1]) + (s_red[2] + s_red[3])) + 1e-6f);

    // wave (pair, half): pair = row group, half = column half (64 regs/lane)
    const int pair = wid & 1;
    const int half = wid >> 1;
    const int col  = half * 64 + lane;

    float e[N_ANCH];
#pragma unroll
    for (int a = 0; a < N_ANCH; ++a) e[a] = s_emb[a * HID + col];  // 2-way: free

    const float da = deg[lane] * inv_nrm;          // lane = anchor index
    const int rbase = blockIdx.x * RPB + pair * (RPB / 2);

    for (int r = 0; r < RPB / 2; ++r) {
        const int row = rbase + r;
        const float sim = deg[row] * da;

        float m = sim;
#pragma unroll
        for (int off = 32; off > 0; off >>= 1) m = fmaxf(m, __shfl_xor(m, off, 64));
        const float ex = __expf(sim - m);
        float sum = ex;
#pragma unroll
        for (int off = 32; off > 0; off >>= 1) sum += __shfl_xor(sum, off, 64);
        s_w[wid][lane] = ex / sum;                 // wave-local; lgkmcnt orders r/w

        float acc = 0.0f;
#pragma unroll
        for (int a4 = 0; a4 < N_ANCH; a4 += 4) {
            f4 w4 = *reinterpret_cast<const f4*>(&s_w[wid][a4]);   // same addr: broadcast
            acc = fmaf(w4.x, e[a4 + 0], acc);
            acc = fmaf(w4.y, e[a4 + 1], acc);
            acc = fmaf(w4.z, e[a4 + 2], acc);
            acc = fmaf(w4.w, e[a4 + 3], acc);
        }
        out[(size_t)row * HID + col] = acc;
    }
}

extern "C" void kernel_launch(void* const* d_in, const int* in_sizes, int n_in,
                              void* d_out, int out_size, void* d_ws, size_t ws_size,
                              hipStream_t stream) {
    const float* adj = (const float*)d_in[0];   // [16384, 16384] f32
    const float* emb = (const float*)d_in[1];   // [64, 128] f32
    float* out = (float*)d_out;                 // [16384, 128] f32

    float* deg      = (float*)d_ws;             // 16384 f32
    float* ssq_part = deg + N_NODES;            // 512 f32

    void* args[] = {(void*)&adj, (void*)&emb, (void*)&out, (void*)&deg, (void*)&ssq_part};
    hipLaunchCooperativeKernel((void*)fused_kernel, dim3(BLOCKS), dim3(256),
                               args, 0, stream);
}

// Round 4
// 179.826 us; speedup vs baseline: 1.3527x; 1.3527x over previous
//
#include <hip/hip_runtime.h>

// AnchorPositionalEncoding (round-2 structure, slimmed K3):
//   adj: [16384, 16384] f32, anchor_emb: [64, 128] f32
//   deg = rowsum(adj); nrm = ||deg||+1e-6; sim = deg*deg[:64]/nrm
//   out = softmax(sim) @ emb -> [16384, 128] f32
//
// K1: wave-per-row streaming rowsum (2048 blocks, NT float4 loads, no per-row
//     barriers) — measured at the ~6.3 TB/s read ceiling.
// K3: norm from K1's per-block ssq partials + softmax @ emb; emb columns read
//     straight from L2 (no LDS staging barrier).

constexpr int N_NODES = 16384;
constexpr int N_ANCH  = 64;
constexpr int HID     = 128;
constexpr int ROWS_PER_BLOCK = 8;                       // 2 rows per wave
constexpr int K1_BLOCKS = N_NODES / ROWS_PER_BLOCK;     // 2048
constexpr int K3_BLOCKS = 1024;                         // 16 rows/block

typedef float f4 __attribute__((ext_vector_type(4)));

// ---------------- K1: row sums + ssq partials ----------------
__global__ __launch_bounds__(256) void rowsum_kernel(const float* __restrict__ adj,
                                                     float* __restrict__ deg,
                                                     float* __restrict__ ssq_part) {
    const int t = threadIdx.x, lane = t & 63, wid = t >> 6;
    const int row0 = blockIdx.x * ROWS_PER_BLOCK + wid * 2;
    float ssq = 0.0f;

    for (int r = 0; r < 2; ++r) {
        const int row = row0 + r;
        const f4* __restrict__ p =
            reinterpret_cast<const f4*>(adj) + (size_t)row * (N_NODES / 4) + lane;
        float s = 0.0f;
        for (int c = 0; c < 4; ++c) {              // 16 x 16B loads in flight
            f4 v[16];                               // static-indexed -> registers
#pragma unroll
            for (int i = 0; i < 16; ++i)
                v[i] = __builtin_nontemporal_load(p + c * 1024 + i * 64);
#pragma unroll
            for (int i = 0; i < 16; ++i)
                s += (v[i].x + v[i].y) + (v[i].z + v[i].w);
        }
#pragma unroll
        for (int off = 32; off > 0; off >>= 1) s += __shfl_down(s, off, 64);
        if (lane == 0) { deg[row] = s; ssq = fmaf(s, s, ssq); }
    }

    __shared__ float sp[4];
    if (lane == 0) sp[wid] = ssq;
    __syncthreads();
    if (t == 0) ssq_part[blockIdx.x] = (sp[0] + sp[1]) + (sp[2] + sp[3]);
}

// ---------------- K3: norm + softmax(sim) @ emb ----------------
// 1024 blocks x 256 threads. wave -> (pair = row group, half = column half);
// each lane caches its emb column (64 regs) straight from L2.
__global__ __launch_bounds__(256) void out_kernel(const float* __restrict__ deg,
                                                  const float* __restrict__ ssq_part,
                                                  const float* __restrict__ emb,
                                                  float* __restrict__ out) {
    __shared__ float s_w[4][N_ANCH];
    __shared__ float s_red[4];

    const int t = threadIdx.x, lane = t & 63, wid = t >> 6;

    // --- norm from 2048 partials (fixed tree, redundant per block) ---
    float ss = 0.0f;
#pragma unroll
    for (int i = 0; i < K1_BLOCKS / 256; ++i) ss += ssq_part[t + i * 256];
#pragma unroll
    for (int off = 32; off > 0; off >>= 1) ss += __shfl_down(ss, off, 64);
    if (lane == 0) s_red[wid] = ss;

    // --- per-lane emb column in registers (64 coalesced 256B loads/wave) ---
    const int pair = wid & 1;            // row group within block
    const int half = wid >> 1;           // column half
    const int col  = half * 64 + lane;
    float e[N_ANCH];
#pragma unroll
    for (int a = 0; a < N_ANCH; ++a) e[a] = emb[a * HID + col];

    __syncthreads();
    const float inv_nrm =
        1.0f / (sqrtf((s_red[0] + s_red[1]) + (s_red[2] + s_red[3])) + 1e-6f);

    const float da = deg[lane] * inv_nrm;          // lane = anchor index
    const int rbase = blockIdx.x * 16 + pair * 8;

#pragma unroll
    for (int r = 0; r < 8; ++r) {
        const int row = rbase + r;
        const float sim = deg[row] * da;

        float m = sim;
#pragma unroll
        for (int off = 32; off > 0; off >>= 1) m = fmaxf(m, __shfl_xor(m, off, 64));
        const float ex = __expf(sim - m);
        float sum = ex;
#pragma unroll
        for (int off = 32; off > 0; off >>= 1) sum += __shfl_xor(sum, off, 64);
        s_w[wid][lane] = ex / sum;                 // wave-local; lgkmcnt orders r/w

        float acc = 0.0f;
#pragma unroll
        for (int a4 = 0; a4 < N_ANCH; a4 += 4) {
            f4 w4 = *reinterpret_cast<const f4*>(&s_w[wid][a4]);   // same addr: broadcast
            acc = fmaf(w4.x, e[a4 + 0], acc);
            acc = fmaf(w4.y, e[a4 + 1], acc);
            acc = fmaf(w4.z, e[a4 + 2], acc);
            acc = fmaf(w4.w, e[a4 + 3], acc);
        }
        out[(size_t)row * HID + col] = acc;
    }
}

extern "C" void kernel_launch(void* const* d_in, const int* in_sizes, int n_in,
                              void* d_out, int out_size, void* d_ws, size_t ws_size,
                              hipStream_t stream) {
    const float* adj = (const float*)d_in[0];   // [16384, 16384] f32
    const float* emb = (const float*)d_in[1];   // [64, 128] f32
    float* out = (float*)d_out;                 // [16384, 128] f32

    float* deg      = (float*)d_ws;             // 16384 f32
    float* ssq_part = deg + N_NODES;            // 2048 f32

    rowsum_kernel<<<K1_BLOCKS, 256, 0, stream>>>(adj, deg, ssq_part);
    out_kernel<<<K3_BLOCKS, 256, 0, stream>>>(deg, ssq_part, emb, out);
}